// Round 6
// baseline (603.574 us; speedup 1.0000x reference)
//
#include <hip/hip_runtime.h>
#include <hip/hip_fp16.h>

// ---------------------------------------------------------------------------
// Round-6 structure: coarse-bucket + LDS-tile accumulate.
//   conv (fp32->fp16 table) ; minihist (782 bucket counts) ; scan (1 block) ;
//   bin (rank in LDS, coalesced flush of 8B payloads into bucket runs) ;
//   accum (1 block/bucket: LDS tile[128][65], ds_add_f32, linear out write).
// Eliminates the exact dst-sort (pack CSR + cursor scatter) that cost ~100us
// in rounds 3-5. Global atomics only on 782 bucket cursors/counters.
// Payload: word0 = (dst&127)<<17 | src  (needs N <= 2^17), word1 = efeat.
// ---------------------------------------------------------------------------

#define NB_SHIFT 7
#define BNODES   128          // nodes per bucket
#define SRC_BITS 17
#define BIN_S    4096         // edges per bin/hist block
#define BIN_T    512
#define ACC_T    512
#define MAXNB    1024

__global__ void conv_half_kernel(const float* __restrict__ g, __half* __restrict__ h, int n) {
    int i = (blockIdx.x * blockDim.x + threadIdx.x) * 8;
    if (i + 7 < n) {
        float4 a = *(const float4*)(g + i);
        float4 b = *(const float4*)(g + i + 4);
        __half2 h0 = __floats2half2_rn(a.x, a.y);
        __half2 h1 = __floats2half2_rn(a.z, a.w);
        __half2 h2 = __floats2half2_rn(b.x, b.y);
        __half2 h3 = __floats2half2_rn(b.z, b.w);
        int4 o;
        o.x = *(int*)&h0; o.y = *(int*)&h1; o.z = *(int*)&h2; o.w = *(int*)&h3;
        *(int4*)(h + i) = o;
    } else {
        for (int k = i; k < n; ++k) h[k] = __float2half(g[k]);
    }
}

__global__ __launch_bounds__(BIN_T) void minihist_kernel(const int* __restrict__ dst,
                                                         int* __restrict__ counts,
                                                         int E, int NB) {
    __shared__ int cnt[MAXNB];
    int t = threadIdx.x;
    for (int i = t; i < MAXNB; i += BIN_T) cnt[i] = 0;
    __syncthreads();
    int e0 = blockIdx.x * BIN_S + t * 8;
    if (e0 + 7 < E) {
        int4 a = *(const int4*)(dst + e0);
        int4 b = *(const int4*)(dst + e0 + 4);
        atomicAdd(&cnt[a.x >> NB_SHIFT], 1);
        atomicAdd(&cnt[a.y >> NB_SHIFT], 1);
        atomicAdd(&cnt[a.z >> NB_SHIFT], 1);
        atomicAdd(&cnt[a.w >> NB_SHIFT], 1);
        atomicAdd(&cnt[b.x >> NB_SHIFT], 1);
        atomicAdd(&cnt[b.y >> NB_SHIFT], 1);
        atomicAdd(&cnt[b.z >> NB_SHIFT], 1);
        atomicAdd(&cnt[b.w >> NB_SHIFT], 1);
    } else {
        for (int k = e0; k < E; ++k) atomicAdd(&cnt[dst[k] >> NB_SHIFT], 1);
    }
    __syncthreads();
    for (int i = t; i < NB; i += BIN_T)
        if (cnt[i]) atomicAdd(&counts[i], cnt[i]);
}

__global__ void scan_kernel(const int* __restrict__ counts,
                            int* __restrict__ goff, int* __restrict__ gcur,
                            int NB) {
    __shared__ int sh[1024];
    int t = threadIdx.x;
    int v = (t < NB) ? counts[t] : 0;
    sh[t] = v;
    __syncthreads();
    for (int o = 1; o < 1024; o <<= 1) {
        int u = (t >= o) ? sh[t - o] : 0;
        __syncthreads();
        sh[t] += u;
        __syncthreads();
    }
    if (t < NB) { goff[t] = sh[t] - v; gcur[t] = sh[t] - v; }
    if (t == 1023) goff[NB] = sh[1023];
}

__global__ __launch_bounds__(BIN_T) void bin_kernel(const int* __restrict__ src,
                                                    const float* __restrict__ ef,
                                                    const int* __restrict__ dst,
                                                    int* __restrict__ gcur,
                                                    int2* __restrict__ gpay, int E) {
    __shared__ int cnt[MAXNB];
    __shared__ int lbase[MAXNB];
    __shared__ int pscan[BIN_T];
    __shared__ int2 stage[BIN_S];
    __shared__ unsigned short sbuck[BIN_S];

    int t = threadIdx.x;
    for (int i = t; i < MAXNB; i += BIN_T) cnt[i] = 0;
    __syncthreads();

    int e0 = blockIdx.x * BIN_S + t * 8;
    int dv[8], sv[8], bk[8], rk[8];
    float ev[8];

    if (e0 + 7 < E) {
        *(int4*)&dv[0]   = *(const int4*)(dst + e0);
        *(int4*)&dv[4]   = *(const int4*)(dst + e0 + 4);
        *(int4*)&sv[0]   = *(const int4*)(src + e0);
        *(int4*)&sv[4]   = *(const int4*)(src + e0 + 4);
        *(float4*)&ev[0] = *(const float4*)(ef + e0);
        *(float4*)&ev[4] = *(const float4*)(ef + e0 + 4);
#pragma unroll
        for (int k = 0; k < 8; ++k) {
            bk[k] = dv[k] >> NB_SHIFT;
            rk[k] = atomicAdd(&cnt[bk[k]], 1);
        }
    } else {
#pragma unroll
        for (int k = 0; k < 8; ++k) {
            if (e0 + k < E) {
                dv[k] = dst[e0 + k];
                sv[k] = src[e0 + k];
                ev[k] = ef[e0 + k];
                bk[k] = dv[k] >> NB_SHIFT;
                rk[k] = atomicAdd(&cnt[bk[k]], 1);
            } else {
                bk[k] = -1;
            }
        }
    }
    __syncthreads();

    // exclusive scan of cnt[0..1023] -> lbase (2 elems/thread)
    int c0 = cnt[2 * t], c1 = cnt[2 * t + 1];
    pscan[t] = c0 + c1;
    __syncthreads();
    for (int o = 1; o < BIN_T; o <<= 1) {
        int u = (t >= o) ? pscan[t - o] : 0;
        __syncthreads();
        pscan[t] += u;
        __syncthreads();
    }
    int ex = pscan[t] - (c0 + c1);
    lbase[2 * t]     = ex;
    lbase[2 * t + 1] = ex + c0;
    __syncthreads();

    // stage ranked payloads
#pragma unroll
    for (int k = 0; k < 8; ++k) {
        if (bk[k] >= 0) {
            int pos = lbase[bk[k]] + rk[k];
            stage[pos] = make_int2(((dv[k] & (BNODES - 1)) << SRC_BITS) | sv[k],
                                   __float_as_int(ev[k]));
            sbuck[pos] = (unsigned short)bk[k];
        }
    }
    // global reserve per bucket; cnt[b] becomes (global_base - local_base)
    for (int i = t; i < MAXNB; i += BIN_T) {
        int c = cnt[i];
        cnt[i] = (c ? atomicAdd(&gcur[i], c) : 0) - lbase[i];
    }
    __syncthreads();

    // coalesced flush: consecutive stage entries -> consecutive global addrs
    int s_total = min(BIN_S, E - blockIdx.x * BIN_S);
    for (int i = t; i < s_total; i += BIN_T) {
        int b = sbuck[i];
        gpay[cnt[b] + i] = stage[i];
    }
}

__global__ __launch_bounds__(ACC_T) void accum_kernel(const __half* __restrict__ hg,
                                                      const int2* __restrict__ gpay,
                                                      const int* __restrict__ goff,
                                                      float* __restrict__ out,
                                                      int N) {
    __shared__ float tile[BNODES * 65];   // 33280 B; stride 65 -> conflict-free
    int t = threadIdx.x;
    for (int i = t; i < BNODES * 65; i += ACC_T) tile[i] = 0.f;
    __syncthreads();

    int b    = blockIdx.x;
    int lo   = goff[b];
    int hi   = goff[b + 1];
    int wave = t >> 6;
    int lane = t & 63;
    const int NW = ACC_T / 64;

    for (int base = lo + wave * 8; base < hi; base += NW * 8) {
        int m = hi - base; if (m > 8) m = 8;
        int2 p = make_int2(0, 0);
        if (lane < m) p = gpay[base + lane];      // 8 edges, 64B coalesced
        for (int k = 0; k < m; ++k) {
            int w0 = __shfl(p.x, k);
            int w1 = __shfl(p.y, k);
            int s  = w0 & ((1 << SRC_BITS) - 1);
            int dr = w0 >> SRC_BITS;
            float v = __half2float(hg[(size_t)s * 64 + lane]);  // 128B coalesced
            atomicAdd(&tile[dr * 65 + lane], v);
            if (lane == 0) atomicAdd(&tile[dr * 65 + 64], __int_as_float(w1));
        }
    }
    __syncthreads();

    long obase = (long)b * (BNODES * 65);
    long total = (long)N * 65;
    int limit = (int)min((long)(BNODES * 65), total - obase);
    for (int i = t; i < limit; i += ACC_T)
        out[obase + i] = tile[i];                 // fully linear store
}

// ---------------------- fallback (always correct) --------------------------

__global__ void atomic_fallback_kernel(const float* __restrict__ gemb,
                                       const float* __restrict__ efeat,
                                       const int* __restrict__ src,
                                       const int* __restrict__ dst,
                                       float* __restrict__ out, int E) {
    int eidx = blockIdx.x * 4 + (threadIdx.x >> 6);
    int lane = threadIdx.x & 63;
    if (eidx >= E) return;
    int s = src[eidx];
    int d = dst[eidx];
    float v = gemb[(size_t)s * 64 + lane];
    atomicAdd(&out[(size_t)d * 65 + lane], v);
    if (lane == 0) atomicAdd(&out[(size_t)d * 65 + 64], efeat[eidx]);
}

// ---------------------------------------------------------------------------

extern "C" void kernel_launch(void* const* d_in, const int* in_sizes, int n_in,
                              void* d_out, int out_size, void* d_ws, size_t ws_size,
                              hipStream_t stream) {
    const float* gemb  = (const float*)d_in[0];   // [N, 64]
    const float* efeat = (const float*)d_in[1];   // [E]
    const int*   src   = (const int*)d_in[2];     // [E]
    const int*   dst   = (const int*)d_in[3];     // [E]
    float*       out   = (float*)d_out;           // [N, 65]

    const int N  = in_sizes[0] / 64;
    const int E  = in_sizes[1];
    const int NB = (N + BNODES - 1) >> NB_SHIFT;

    auto aln = [](size_t x) { return (x + 15) & ~(size_t)15; };
    size_t off_counts = 0;
    size_t off_goff   = off_counts + aln((size_t)NB * 4);
    size_t off_gcur   = off_goff   + aln((size_t)(NB + 1) * 4);
    size_t off_gpay   = off_gcur   + aln((size_t)NB * 4);
    size_t off_hg     = off_gpay   + aln((size_t)E * 8);
    size_t needed     = off_hg     + (size_t)N * 64 * 2;

    if (N > (1 << SRC_BITS) || NB > MAXNB || ws_size < needed) {
        hipMemsetAsync(d_out, 0, (size_t)out_size * sizeof(float), stream);
        int blocks = (E + 3) / 4;
        atomic_fallback_kernel<<<blocks, 256, 0, stream>>>(gemb, efeat, src, dst, out, E);
        return;
    }

    char*   ws     = (char*)d_ws;
    int*    counts = (int*)(ws + off_counts);
    int*    goff   = (int*)(ws + off_goff);
    int*    gcur   = (int*)(ws + off_gcur);
    int2*   gpay   = (int2*)(ws + off_gpay);
    __half* hg     = (__half*)(ws + off_hg);

    hipMemsetAsync(counts, 0, (size_t)NB * 4, stream);

    int n_emb    = N * 64;
    int c_blocks = ((n_emb + 7) / 8 + 255) / 256;
    conv_half_kernel<<<c_blocks, 256, 0, stream>>>(gemb, hg, n_emb);

    int e_blocks = (E + BIN_S - 1) / BIN_S;
    minihist_kernel<<<e_blocks, BIN_T, 0, stream>>>(dst, counts, E, NB);
    scan_kernel<<<1, 1024, 0, stream>>>(counts, goff, gcur, NB);
    bin_kernel<<<e_blocks, BIN_T, 0, stream>>>(src, efeat, dst, gcur, gpay, E);
    accum_kernel<<<NB, ACC_T, 0, stream>>>(hg, gpay, goff, out, N);
}

// Round 7
// 158.190 us; speedup vs baseline: 3.8155x; 3.8155x over previous
//
#include <hip/hip_runtime.h>
#include <hip/hip_fp16.h>

// ---------------------------------------------------------------------------
// Round-7 structure: coarse-bucket binning (proven ~25us in r6) + fused
// in-LDS counting-sort + register-accumulate gather (replaces r6's 571us
// LDS-atomic accumulator, which was a serial shfl+atomic latency chain).
//   conv (fp32->fp16 table) ; minihist ; scan ; bin (coalesced 8B payload
//   flush into bucket runs) ; sortaccum (1 block/bucket: counting-sort chunk
//   in LDS -> 8 waves x 16 node-slots, reg accumulation, linear out write).
// Payload word0 = (dst&127)<<17 | src  (needs N <= 2^17), word1 = efeat.
// ---------------------------------------------------------------------------

#define NB_SHIFT 7
#define BNODES   128          // nodes per bucket
#define SRC_BITS 17
#define SRC_MASK ((1 << SRC_BITS) - 1)
#define BIN_S    4096         // edges per bin/hist block
#define BIN_T    512
#define ACC_T    512          // 8 waves
#define SGCAP    2048         // sort-chunk capacity (edges)
#define MAXNB    1024

__global__ void conv_half_kernel(const float* __restrict__ g, __half* __restrict__ h, int n) {
    int i = (blockIdx.x * blockDim.x + threadIdx.x) * 8;
    if (i + 7 < n) {
        float4 a = *(const float4*)(g + i);
        float4 b = *(const float4*)(g + i + 4);
        __half2 h0 = __floats2half2_rn(a.x, a.y);
        __half2 h1 = __floats2half2_rn(a.z, a.w);
        __half2 h2 = __floats2half2_rn(b.x, b.y);
        __half2 h3 = __floats2half2_rn(b.z, b.w);
        int4 o;
        o.x = *(int*)&h0; o.y = *(int*)&h1; o.z = *(int*)&h2; o.w = *(int*)&h3;
        *(int4*)(h + i) = o;
    } else {
        for (int k = i; k < n; ++k) h[k] = __float2half(g[k]);
    }
}

__global__ __launch_bounds__(BIN_T) void minihist_kernel(const int* __restrict__ dst,
                                                         int* __restrict__ counts,
                                                         int E, int NB) {
    __shared__ int cnt[MAXNB];
    int t = threadIdx.x;
    for (int i = t; i < MAXNB; i += BIN_T) cnt[i] = 0;
    __syncthreads();
    int e0 = blockIdx.x * BIN_S + t * 8;
    if (e0 + 7 < E) {
        int4 a = *(const int4*)(dst + e0);
        int4 b = *(const int4*)(dst + e0 + 4);
        atomicAdd(&cnt[a.x >> NB_SHIFT], 1);
        atomicAdd(&cnt[a.y >> NB_SHIFT], 1);
        atomicAdd(&cnt[a.z >> NB_SHIFT], 1);
        atomicAdd(&cnt[a.w >> NB_SHIFT], 1);
        atomicAdd(&cnt[b.x >> NB_SHIFT], 1);
        atomicAdd(&cnt[b.y >> NB_SHIFT], 1);
        atomicAdd(&cnt[b.z >> NB_SHIFT], 1);
        atomicAdd(&cnt[b.w >> NB_SHIFT], 1);
    } else {
        for (int k = e0; k < E; ++k) atomicAdd(&cnt[dst[k] >> NB_SHIFT], 1);
    }
    __syncthreads();
    for (int i = t; i < NB; i += BIN_T)
        if (cnt[i]) atomicAdd(&counts[i], cnt[i]);
}

__global__ void scan_kernel(const int* __restrict__ counts,
                            int* __restrict__ goff, int* __restrict__ gcur,
                            int NB) {
    __shared__ int sh[1024];
    int t = threadIdx.x;
    int v = (t < NB) ? counts[t] : 0;
    sh[t] = v;
    __syncthreads();
    for (int o = 1; o < 1024; o <<= 1) {
        int u = (t >= o) ? sh[t - o] : 0;
        __syncthreads();
        sh[t] += u;
        __syncthreads();
    }
    if (t < NB) { goff[t] = sh[t] - v; gcur[t] = sh[t] - v; }
    if (t == 1023) goff[NB] = sh[1023];
}

__global__ __launch_bounds__(BIN_T) void bin_kernel(const int* __restrict__ src,
                                                    const float* __restrict__ ef,
                                                    const int* __restrict__ dst,
                                                    int* __restrict__ gcur,
                                                    int2* __restrict__ gpay, int E) {
    __shared__ int cnt[MAXNB];
    __shared__ int lbase[MAXNB];
    __shared__ int pscan[BIN_T];
    __shared__ int2 stage[BIN_S];
    __shared__ unsigned short sbuck[BIN_S];

    int t = threadIdx.x;
    for (int i = t; i < MAXNB; i += BIN_T) cnt[i] = 0;
    __syncthreads();

    int e0 = blockIdx.x * BIN_S + t * 8;
    int dv[8], sv[8], bk[8], rk[8];
    float ev[8];

    if (e0 + 7 < E) {
        *(int4*)&dv[0]   = *(const int4*)(dst + e0);
        *(int4*)&dv[4]   = *(const int4*)(dst + e0 + 4);
        *(int4*)&sv[0]   = *(const int4*)(src + e0);
        *(int4*)&sv[4]   = *(const int4*)(src + e0 + 4);
        *(float4*)&ev[0] = *(const float4*)(ef + e0);
        *(float4*)&ev[4] = *(const float4*)(ef + e0 + 4);
#pragma unroll
        for (int k = 0; k < 8; ++k) {
            bk[k] = dv[k] >> NB_SHIFT;
            rk[k] = atomicAdd(&cnt[bk[k]], 1);
        }
    } else {
#pragma unroll
        for (int k = 0; k < 8; ++k) {
            if (e0 + k < E) {
                dv[k] = dst[e0 + k];
                sv[k] = src[e0 + k];
                ev[k] = ef[e0 + k];
                bk[k] = dv[k] >> NB_SHIFT;
                rk[k] = atomicAdd(&cnt[bk[k]], 1);
            } else {
                bk[k] = -1;
            }
        }
    }
    __syncthreads();

    // exclusive scan of cnt[0..1023] -> lbase (2 elems/thread)
    int c0 = cnt[2 * t], c1 = cnt[2 * t + 1];
    pscan[t] = c0 + c1;
    __syncthreads();
    for (int o = 1; o < BIN_T; o <<= 1) {
        int u = (t >= o) ? pscan[t - o] : 0;
        __syncthreads();
        pscan[t] += u;
        __syncthreads();
    }
    int ex = pscan[t] - (c0 + c1);
    lbase[2 * t]     = ex;
    lbase[2 * t + 1] = ex + c0;
    __syncthreads();

    // stage ranked payloads
#pragma unroll
    for (int k = 0; k < 8; ++k) {
        if (bk[k] >= 0) {
            int pos = lbase[bk[k]] + rk[k];
            stage[pos] = make_int2(((dv[k] & (BNODES - 1)) << SRC_BITS) | sv[k],
                                   __float_as_int(ev[k]));
            sbuck[pos] = (unsigned short)bk[k];
        }
    }
    // global reserve per bucket; cnt[b] becomes (global_base - local_base)
    for (int i = t; i < MAXNB; i += BIN_T) {
        int c = cnt[i];
        cnt[i] = (c ? atomicAdd(&gcur[i], c) : 0) - lbase[i];
    }
    __syncthreads();

    // coalesced flush: consecutive stage entries -> consecutive global addrs
    int s_total = min(BIN_S, E - blockIdx.x * BIN_S);
    for (int i = t; i < s_total; i += BIN_T) {
        int b = sbuck[i];
        gpay[cnt[b] + i] = stage[i];
    }
}

// Fused counting-sort + register gather. One block per bucket (128 nodes),
// 8 waves; wave w owns node-slots r = i*8+w (i=0..15). Per chunk of <=2048
// edges: count/rank per node, scan 128 counters, place sorted in LDS stage,
// then each wave walks its slots' sublists: LDS-broadcast payload, coalesced
// 128B fp16 row load, register accumulate (no atomics, unroll-4 MLP).
__global__ __launch_bounds__(ACC_T) void sortaccum_kernel(const __half* __restrict__ hg,
                                                          const int2* __restrict__ gpay,
                                                          const int* __restrict__ goff,
                                                          float* __restrict__ out,
                                                          int N) {
    __shared__ int  cnt[BNODES];
    __shared__ int  lbase[BNODES];
    __shared__ int  sbuf[BNODES];
    __shared__ int2 stage[SGCAP];   // 16 KB

    const int t    = threadIdx.x;
    const int b    = blockIdx.x;
    const int wave = t >> 6;
    const int lane = t & 63;
    const int lo   = goff[b];
    const int hi   = goff[b + 1];

    float acc[16];
    float eacc[16];
#pragma unroll
    for (int i = 0; i < 16; ++i) { acc[i] = 0.f; eacc[i] = 0.f; }

    for (int cbase = lo; cbase < hi; cbase += SGCAP) {
        const int csize = min(SGCAP, hi - cbase);

        if (t < BNODES) cnt[t] = 0;
        __syncthreads();

        // load + rank (4 payloads per thread, coalesced)
        int2 pv[4]; int rk[4]; int dr[4];
#pragma unroll
        for (int k = 0; k < 4; ++k) {
            int idx = t + k * ACC_T;
            dr[k] = -1;
            if (idx < csize) {
                pv[k] = gpay[cbase + idx];
                dr[k] = pv[k].x >> SRC_BITS;
                rk[k] = atomicAdd(&cnt[dr[k]], 1);
            }
        }
        __syncthreads();

        // exclusive scan of cnt[0..127] (all threads hit barriers)
        int v = (t < BNODES) ? cnt[t] : 0;
        if (t < BNODES) sbuf[t] = v;
        __syncthreads();
        for (int o = 1; o < BNODES; o <<= 1) {
            int u = (t < BNODES && t >= o) ? sbuf[t - o] : 0;
            __syncthreads();
            if (t < BNODES) sbuf[t] += u;
            __syncthreads();
        }
        if (t < BNODES) lbase[t] = sbuf[t] - v;
        __syncthreads();

        // place sorted
#pragma unroll
        for (int k = 0; k < 4; ++k)
            if (dr[k] >= 0) stage[lbase[dr[k]] + rk[k]] = pv[k];
        __syncthreads();

        // accumulate: wave w handles slots r = i*8 + w
#pragma unroll
        for (int i = 0; i < 16; ++i) {
            const int r  = i * 8 + wave;
            const int s0 = lbase[r];
            const int c  = cnt[r];
            float a0 = 0.f, a1 = 0.f, a2 = 0.f, a3 = 0.f;
            float e03 = 0.f;
            int j = 0;
            for (; j + 3 < c; j += 4) {
                int2 p0 = stage[s0 + j];
                int2 p1 = stage[s0 + j + 1];
                int2 p2 = stage[s0 + j + 2];
                int2 p3 = stage[s0 + j + 3];
                float v0 = __half2float(hg[(size_t)(p0.x & SRC_MASK) * 64 + lane]);
                float v1 = __half2float(hg[(size_t)(p1.x & SRC_MASK) * 64 + lane]);
                float v2 = __half2float(hg[(size_t)(p2.x & SRC_MASK) * 64 + lane]);
                float v3 = __half2float(hg[(size_t)(p3.x & SRC_MASK) * 64 + lane]);
                a0 += v0; a1 += v1; a2 += v2; a3 += v3;
                e03 += __int_as_float(p0.y) + __int_as_float(p1.y) +
                       __int_as_float(p2.y) + __int_as_float(p3.y);
            }
            for (; j < c; ++j) {
                int2 p = stage[s0 + j];
                a0  += __half2float(hg[(size_t)(p.x & SRC_MASK) * 64 + lane]);
                e03 += __int_as_float(p.y);
            }
            acc[i]  += (a0 + a1) + (a2 + a3);
            eacc[i] += e03;
        }
        __syncthreads();   // stage/cnt reused next chunk
    }

    // write output rows once, near-linear
#pragma unroll
    for (int i = 0; i < 16; ++i) {
        const int r    = i * 8 + wave;
        const int node = b * BNODES + r;
        if (node < N) {
            out[(size_t)node * 65 + lane] = acc[i];
            if (lane == 0) out[(size_t)node * 65 + 64] = eacc[i];
        }
    }
}

// ---------------------- fallback (always correct) --------------------------

__global__ void atomic_fallback_kernel(const float* __restrict__ gemb,
                                       const float* __restrict__ efeat,
                                       const int* __restrict__ src,
                                       const int* __restrict__ dst,
                                       float* __restrict__ out, int E) {
    int eidx = blockIdx.x * 4 + (threadIdx.x >> 6);
    int lane = threadIdx.x & 63;
    if (eidx >= E) return;
    int s = src[eidx];
    int d = dst[eidx];
    float v = gemb[(size_t)s * 64 + lane];
    atomicAdd(&out[(size_t)d * 65 + lane], v);
    if (lane == 0) atomicAdd(&out[(size_t)d * 65 + 64], efeat[eidx]);
}

// ---------------------------------------------------------------------------

extern "C" void kernel_launch(void* const* d_in, const int* in_sizes, int n_in,
                              void* d_out, int out_size, void* d_ws, size_t ws_size,
                              hipStream_t stream) {
    const float* gemb  = (const float*)d_in[0];   // [N, 64]
    const float* efeat = (const float*)d_in[1];   // [E]
    const int*   src   = (const int*)d_in[2];     // [E]
    const int*   dst   = (const int*)d_in[3];     // [E]
    float*       out   = (float*)d_out;           // [N, 65]

    const int N  = in_sizes[0] / 64;
    const int E  = in_sizes[1];
    const int NB = (N + BNODES - 1) >> NB_SHIFT;

    auto aln = [](size_t x) { return (x + 15) & ~(size_t)15; };
    size_t off_counts = 0;
    size_t off_goff   = off_counts + aln((size_t)NB * 4);
    size_t off_gcur   = off_goff   + aln((size_t)(NB + 1) * 4);
    size_t off_gpay   = off_gcur   + aln((size_t)NB * 4);
    size_t off_hg     = off_gpay   + aln((size_t)E * 8);
    size_t needed     = off_hg     + (size_t)N * 64 * 2;

    if (N > (1 << SRC_BITS) || NB > MAXNB || ws_size < needed) {
        hipMemsetAsync(d_out, 0, (size_t)out_size * sizeof(float), stream);
        int blocks = (E + 3) / 4;
        atomic_fallback_kernel<<<blocks, 256, 0, stream>>>(gemb, efeat, src, dst, out, E);
        return;
    }

    char*   ws     = (char*)d_ws;
    int*    counts = (int*)(ws + off_counts);
    int*    goff   = (int*)(ws + off_goff);
    int*    gcur   = (int*)(ws + off_gcur);
    int2*   gpay   = (int2*)(ws + off_gpay);
    __half* hg     = (__half*)(ws + off_hg);

    hipMemsetAsync(counts, 0, (size_t)NB * 4, stream);

    int n_emb    = N * 64;
    int c_blocks = ((n_emb + 7) / 8 + 255) / 256;
    conv_half_kernel<<<c_blocks, 256, 0, stream>>>(gemb, hg, n_emb);

    int e_blocks = (E + BIN_S - 1) / BIN_S;
    minihist_kernel<<<e_blocks, BIN_T, 0, stream>>>(dst, counts, E, NB);
    scan_kernel<<<1, 1024, 0, stream>>>(counts, goff, gcur, NB);
    bin_kernel<<<e_blocks, BIN_T, 0, stream>>>(src, efeat, dst, gcur, gpay, E);
    sortaccum_kernel<<<NB, ACC_T, 0, stream>>>(hg, gpay, goff, out, N);
}